// Round 1
// 370.929 us; speedup vs baseline: 1.0190x; 1.0190x over previous
//
#include <hip/hip_runtime.h>
#include <math.h>

#define BB     8
#define NN     1024
#define EE     256
#define DMODEL 64
#define HH     4
#define DHH    16

// workspace layout (float offsets)
#define WS_Q    0           // [B][H][N][16]   = 524288
#define WS_K    524288      // [B][H][N][16]   = 524288
#define WS_GQ   1048576     // [2][B][H][N][16] = 1048576
#define WS_GKT  2097152     // [2][B][H][16][N] = 1048576
// total 3145728 floats = 12582912 bytes

// ---------------------------------------------------------------------------
// K1: fused embedding + Q/K projection.  block = 256 = 4 positions x 64 dims
// ---------------------------------------------------------------------------
__global__ __launch_bounds__(256) void qk_kernel(
    const float* __restrict__ x, const float* __restrict__ W_emb,
    const float* __restrict__ b_emb, const float* __restrict__ W_q,
    const float* __restrict__ b_q, const float* __restrict__ W_k,
    const float* __restrict__ b_k, float* __restrict__ ws) {
  __shared__ float semb[4][DMODEL];
  const int tid = threadIdx.x;
  const int p = tid >> 6, d = tid & 63;
  const int pos = blockIdx.x * 4 + p;  // b*N + n
  const float x0 = x[pos * 2 + 0];
  const float x1 = x[pos * 2 + 1];
  semb[p][d] = fmaf(x0, W_emb[d], fmaf(x1, W_emb[DMODEL + d], b_emb[d]));
  __syncthreads();
  float accq = b_q[d], acck = b_k[d];
#pragma unroll 8
  for (int e = 0; e < DMODEL; ++e) {
    const float ev = semb[p][e];
    accq = fmaf(ev, W_q[e * DMODEL + d], accq);
    acck = fmaf(ev, W_k[e * DMODEL + d], acck);
  }
  const int b = pos >> 10, n = pos & (NN - 1);
  const int h = d >> 4, c = d & 15;
  const int oidx = ((b * HH + h) * NN + n) * DHH + c;
  ws[WS_Q + oidx] = accq;
  ws[WS_K + oidx] = acck;
}

// ---------------------------------------------------------------------------
// K2: edge-proj (fused, in LDS) + gq/gk^T with div.
// blockIdx = mat*16 + sub; mat=(br*8+b)*4+h; sub = nchunk(0..3) x cq(0..3).
// Each thread: one n, 4 q-channels + 4 k-channels (cq quarter).
// ---------------------------------------------------------------------------
__global__ __launch_bounds__(256) void gqgk_kernel(
    const float* __restrict__ G, const float* __restrict__ C_G,
    const float* __restrict__ edge, const float* __restrict__ C_edge,
    const float* __restrict__ W_eq, const float* __restrict__ b_eq,
    const float* __restrict__ W_ek, const float* __restrict__ b_ek,
    const float* __restrict__ W_ceq, const float* __restrict__ b_ceq,
    const float* __restrict__ W_cek, const float* __restrict__ b_cek,
    float* __restrict__ ws) {
  __shared__ float seq[EE * 4];  // 4 KB
  __shared__ float sek[EE * 4];  // 4 KB
  const int sub = blockIdx.x & 15;
  const int mat = blockIdx.x >> 4;  // (br*8+b)*4+h
  const int h = mat & 3;
  const int b = (mat >> 2) & 7;
  const int br = mat >> 5;
  const int nchunk = sub >> 2;
  const int c0 = (sub & 3) * 4;  // channel quarter
  const int tid = threadIdx.x;
  const int n = (nchunk << 8) + tid;

  const float* __restrict__ Wq = br ? W_ceq : W_eq;
  const float* __restrict__ Wk = br ? W_cek : W_ek;
  const float* __restrict__ bq = br ? b_ceq : b_eq;
  const float* __restrict__ bk = br ? b_cek : b_ek;
  const float* __restrict__ esrc = br ? C_edge : edge;

  // ---- staging: thread tid = edge row e; compute 4 eq + 4 ek channels ----
  {
    float in[16];
    const float4* s4 = (const float4*)(esrc + ((size_t)(b * HH + h) * EE + tid) * 16);
#pragma unroll
    for (int i = 0; i < 4; ++i) {
      const float4 v = s4[i];
      in[4 * i + 0] = v.x; in[4 * i + 1] = v.y;
      in[4 * i + 2] = v.z; in[4 * i + 3] = v.w;
    }
    float aq[4], ak[4];
#pragma unroll
    for (int j = 0; j < 4; ++j) { aq[j] = bq[c0 + j]; ak[j] = bk[c0 + j]; }
#pragma unroll
    for (int cp = 0; cp < 16; ++cp) {
      const float iv = in[cp];
#pragma unroll
      for (int j = 0; j < 4; ++j) {
        aq[j] = fmaf(iv, Wq[cp * 16 + c0 + j], aq[j]);
        ak[j] = fmaf(iv, Wk[cp * 16 + c0 + j], ak[j]);
      }
    }
#pragma unroll
    for (int j = 0; j < 4; ++j) { seq[tid * 4 + j] = aq[j]; sek[tid * 4 + j] = ak[j]; }
  }
  __syncthreads();

  // ---- main loop over E ----
  const float* __restrict__ Gm = br ? C_G : G;
  const float* __restrict__ gcol = Gm + (size_t)b * EE * NN + n;
  float accq[4] = {0.f, 0.f, 0.f, 0.f};
  float acck[4] = {0.f, 0.f, 0.f, 0.f};
  float div = 0.f;
#pragma unroll 8
  for (int e = 0; e < EE; ++e) {
    const float g = gcol[e * NN];
    div += g;
#pragma unroll
    for (int c = 0; c < 4; ++c) {
      accq[c] = fmaf(g, seq[e * 4 + c], accq[c]);
      acck[c] = fmaf(g, sek[e * 4 + c], acck[c]);
    }
  }
  const float inv = 1.0f / div;
  const int qidx = ((b * HH + h) * NN + n) * 16 + c0;
  const float* __restrict__ qrow = ws + WS_Q + qidx;
  const float* __restrict__ krow = ws + WS_K + qidx;
  float* __restrict__ gq = ws + WS_GQ + (mat * NN + n) * 16 + c0;
  float* __restrict__ gkT = ws + WS_GKT + mat * 16 * NN + n;
  float4 qo;
  qo.x = qrow[0] + accq[0] * inv;
  qo.y = qrow[1] + accq[1] * inv;
  qo.z = qrow[2] + accq[2] * inv;
  qo.w = qrow[3] + accq[3] * inv;
  *(float4*)gq = qo;
#pragma unroll
  for (int c = 0; c < 4; ++c)
    gkT[(c0 + c) * NN] = krow[c] + acck[c] * inv;
}

// ---------------------------------------------------------------------------
// K3 (rewritten): scores + softmax + write, no gk^T LDS staging.
// block = 256 thr = 4 waves; block owns (mat, 16-row tile); wave owns 4 rows
// x 1024 cols; lane owns cols {4*lane + 256*t + j}.  gk^T (64 KB/mat) is
// read straight from global — it L2-resides (re-read 268 MB total ≈ 8 µs at
// L2 BW) — as dense dwordx4 (1 KB/wave-instr).  Stores are dwordx4 too.
// Only gq (1 KB) goes through LDS (wave-uniform broadcast reads).
// 4 blocks/CU resident -> load/compute/store phases of different blocks
// overlap instead of barrier-serializing on a single monolithic block.
// ---------------------------------------------------------------------------
__global__ __launch_bounds__(256, 4) void attn_kernel(
    const float* __restrict__ ws, float* __restrict__ out) {
  __shared__ float sgq[16 * 16];  // 1 KB: 16 rows x 16 channels
  const int idx = blockIdx.x;
  const int rb = idx & 63;        // 16-row tile index
  const int mat = idx >> 6;       // (br*8+b)*4+h == output matrix index
  const float* __restrict__ gkTp = ws + WS_GKT + (size_t)mat * 16 * NN;
  const float* __restrict__ gqp =
      ws + WS_GQ + ((size_t)mat * NN + (size_t)rb * 16) * 16;
  const int tid = threadIdx.x;
  if (tid < 64) ((float4*)sgq)[tid] = ((const float4*)gqp)[tid];
  __syncthreads();
  const int wave = tid >> 6, lane = tid & 63;
  const int r0 = wave * 4;
  const int col0 = lane * 4;

  float s[4][16];
#pragma unroll
  for (int r = 0; r < 4; ++r)
#pragma unroll
    for (int t = 0; t < 16; ++t) s[r][t] = 0.f;

#pragma unroll 4
  for (int c = 0; c < 16; ++c) {
    float4 g[4];
#pragma unroll
    for (int t = 0; t < 4; ++t)
      g[t] = *(const float4*)(gkTp + c * NN + col0 + 256 * t);
#pragma unroll
    for (int r = 0; r < 4; ++r) {
      const float qv = sgq[(r0 + r) * 16 + c];  // LDS broadcast (uniform)
#pragma unroll
      for (int t = 0; t < 4; ++t) {
        s[r][4 * t + 0] = fmaf(qv, g[t].x, s[r][4 * t + 0]);
        s[r][4 * t + 1] = fmaf(qv, g[t].y, s[r][4 * t + 1]);
        s[r][4 * t + 2] = fmaf(qv, g[t].z, s[r][4 * t + 2]);
        s[r][4 * t + 3] = fmaf(qv, g[t].w, s[r][4 * t + 3]);
      }
    }
  }

#pragma unroll
  for (int r = 0; r < 4; ++r) {
    float m = s[r][0];
#pragma unroll
    for (int t = 1; t < 16; ++t) m = fmaxf(m, s[r][t]);
#pragma unroll
    for (int off = 32; off; off >>= 1) m = fmaxf(m, __shfl_xor(m, off));
    float sum = 0.f;
#pragma unroll
    for (int t = 0; t < 16; ++t) {
      s[r][t] = __expf((s[r][t] - m) * 0.125f);  // softmax(score/sqrt(64))
      sum += s[r][t];
    }
#pragma unroll
    for (int off = 32; off; off >>= 1) sum += __shfl_xor(sum, off);
    const float inv = 1.0f / sum;
    float* __restrict__ orow =
        out + ((size_t)mat * NN + (size_t)(rb * 16 + r0 + r)) * NN;
#pragma unroll
    for (int t = 0; t < 4; ++t) {
      float4 o;
      o.x = s[r][4 * t + 0] * inv;
      o.y = s[r][4 * t + 1] * inv;
      o.z = s[r][4 * t + 2] * inv;
      o.w = s[r][4 * t + 3] * inv;
      *(float4*)(orow + col0 + 256 * t) = o;
    }
  }
}

// ---------------------------------------------------------------------------
extern "C" void kernel_launch(void* const* d_in, const int* in_sizes, int n_in,
                              void* d_out, int out_size, void* d_ws,
                              size_t ws_size, hipStream_t stream) {
  const float* x      = (const float*)d_in[0];
  const float* edge   = (const float*)d_in[1];
  const float* C_edge = (const float*)d_in[2];
  const float* G      = (const float*)d_in[3];
  const float* C_G    = (const float*)d_in[4];
  const float* W_emb  = (const float*)d_in[5];
  const float* b_emb  = (const float*)d_in[6];
  const float* W_q    = (const float*)d_in[7];
  const float* b_q    = (const float*)d_in[8];
  const float* W_k    = (const float*)d_in[9];
  const float* b_k    = (const float*)d_in[10];
  const float* W_eq   = (const float*)d_in[11];
  const float* b_eq   = (const float*)d_in[12];
  const float* W_ek   = (const float*)d_in[13];
  const float* b_ek   = (const float*)d_in[14];
  const float* W_ceq  = (const float*)d_in[15];
  const float* b_ceq  = (const float*)d_in[16];
  const float* W_cek  = (const float*)d_in[17];
  const float* b_cek  = (const float*)d_in[18];
  float* ws = (float*)d_ws;
  float* out = (float*)d_out;

  hipLaunchKernelGGL(qk_kernel, dim3(BB * NN / 4), dim3(256), 0, stream, x,
                     W_emb, b_emb, W_q, b_q, W_k, b_k, ws);
  hipLaunchKernelGGL(gqgk_kernel, dim3(2 * BB * HH * 16), dim3(256), 0, stream,
                     G, C_G, edge, C_edge, W_eq, b_eq, W_ek, b_ek, W_ceq,
                     b_ceq, W_cek, b_cek, ws);
  hipLaunchKernelGGL(attn_kernel, dim3(2 * BB * HH * 64), dim3(256), 0,
                     stream, ws, out);
}